// Round 11
// baseline (359.970 us; speedup 1.0000x reference)
//
#include <hip/hip_runtime.h>
#include <hip/hip_fp16.h>

#define N_NODES 100000
#define EDGES   1600000
#define D       128
#define BN_EPS  1e-5f
#define TM      64                        // rows per GEMM tile
#define NT      ((N_NODES + TM - 1) / TM) // 1563 row tiles
#define GGRID   782                       // gemm grid-stride: 2 tiles/block
#define NB      782                       // 128-node buckets
#define SLOT    4800                      // per-bucket slot: mean 4092 + 11 sigma
#define L1E     8                         // ei entries per thread (emits 2 pairs each)
#define L1TILE  (256 * L1E)               // 2048 ei entries per tile -> 782 tiles
#define GBLKS   2048                      // gather blocks: 8/CU -> full occupancy
#define GWAVES  (GBLKS * 4)
#define NREP    32                        // BN-stat replicas

typedef __attribute__((ext_vector_type(8))) short short8;
typedef __attribute__((ext_vector_type(4))) float f32x4;

__device__ __forceinline__ unsigned short bf_hi(float f) {
    unsigned u = __float_as_uint(f);
    unsigned t = u + 0x7FFF + ((u >> 16) & 1);
    return (unsigned short)(t >> 16);
}
__device__ __forceinline__ float bf_val(unsigned short h) {
    return __uint_as_float(((unsigned)h) << 16);
}
// split 8 contiguous fp32 into bf16 hi/lo fragments (for inline W staging)
__device__ __forceinline__ void split8(const float* __restrict__ p, short8* hi, short8* lo) {
    short8 h, l;
#pragma unroll
    for (int i = 0; i < 8; ++i) {
        float f = p[i];
        unsigned short hh = bf_hi(f);
        ((unsigned short*)&h)[i] = (short)hh;
        ((unsigned short*)&l)[i] = (short)bf_hi(f - bf_val(hh));
    }
    *hi = h; *lo = l;
}

// ---------------------------------------------------------------------------
// F1: heterogeneous fused kernel.
//   blocks [0, GGRID)          : gemm0  y = x @ W1^T -> fp16 mirror (W1 split inline)
//   blocks [GGRID, GGRID+782)  : edge partition into 128-node buckets
// pairs entry: (local_dst<<17) | src   (local_dst < 128, src < 2^17)
// ---------------------------------------------------------------------------
__launch_bounds__(256)
__global__ void fused_pg(const float* __restrict__ x,
                         const float* __restrict__ W1,
                         __half* __restrict__ yh,
                         const int* __restrict__ ei, int* __restrict__ gcur,
                         int* __restrict__ pairs) {
    __shared__ unsigned short sH[TM][136];
    __shared__ unsigned short sL[TM][136];
    const int tid = threadIdx.x;

    if (blockIdx.x >= GGRID) {
        // ---------------- partition path ----------------
        int* cnt   = (int*)&sH[0][0];        // 782 ints
        int* cbase = cnt + NB;               // 782 ints  (6.3 KB total, aliased)
        for (int i = tid; i < NB; i += 256) cnt[i] = 0;
        __syncthreads();

        int bbA[L1E], rrA[L1E], pkA[L1E];
        int bbB[L1E], rrB[L1E], pkB[L1E];
        const int t0 = (blockIdx.x - GGRID) * L1TILE + tid;
#pragma unroll
        for (int j = 0; j < L1E; ++j) {
            int t = t0 + j * 256;
            bbA[j] = -1;
            bbB[j] = -1;
            if (t < EDGES) {
                int s = ei[t];
                int d = ei[EDGES + t];
                bbA[j] = d >> 7;                     // aggr[d] += y[s]
                pkA[j] = ((d & 127) << 17) | s;
                rrA[j] = atomicAdd(&cnt[bbA[j]], 1);
                bbB[j] = s >> 7;                     // aggr[s] += y[d]
                pkB[j] = ((s & 127) << 17) | d;
                rrB[j] = atomicAdd(&cnt[bbB[j]], 1);
            }
        }
        __syncthreads();
        for (int i = tid; i < NB; i += 256) {
            int c = cnt[i];
            cbase[i] = c ? (i * SLOT + atomicAdd(&gcur[i], c)) : 0;
        }
        __syncthreads();
#pragma unroll
        for (int j = 0; j < L1E; ++j) {
            if (bbA[j] >= 0) {
                pairs[cbase[bbA[j]] + rrA[j]] = pkA[j];
                pairs[cbase[bbB[j]] + rrB[j]] = pkB[j];
            }
        }
        return;
    }

    // ---------------- gemm0 path ----------------
    const int wv  = tid >> 6;
    const int ln  = tid & 63;
    const int lc  = ln & 15;
    const int qd  = ln >> 4;
    const int sr  = tid >> 5;      // staging row base (0..7)
    const int sc4 = tid & 31;      // staging float4 chunk

    short8 Bh[4][2], Bl[4][2];
#pragma unroll
    for (int kk = 0; kk < 4; ++kk)
#pragma unroll
        for (int tl = 0; tl < 2; ++tl) {
            int woff = (wv * 32 + tl * 16 + lc) * D + kk * 32 + qd * 8;
            split8(W1 + woff, &Bh[kk][tl], &Bl[kk][tl]);
        }

    float4 pf[8];
    int tile = blockIdx.x;
#pragma unroll
    for (int i = 0; i < 8; ++i) {
        int gr = tile * TM + sr + i * 8;
        pf[i] = make_float4(0.f, 0.f, 0.f, 0.f);
        if (gr < N_NODES)
            pf[i] = *(const float4*)(x + (long long)gr * D + sc4 * 4);
    }

    while (tile < NT) {
#pragma unroll
        for (int i = 0; i < 8; ++i) {
            float4 v = pf[i];
            unsigned short h0 = bf_hi(v.x), h1b = bf_hi(v.y), h2 = bf_hi(v.z), h3 = bf_hi(v.w);
            unsigned short l0 = bf_hi(v.x - bf_val(h0)), l1 = bf_hi(v.y - bf_val(h1b));
            unsigned short l2 = bf_hi(v.z - bf_val(h2)), l3 = bf_hi(v.w - bf_val(h3));
            int r = sr + i * 8;
            *(uint2*)&sH[r][sc4 * 4] = make_uint2((unsigned)h0 | ((unsigned)h1b << 16),
                                                  (unsigned)h2 | ((unsigned)h3 << 16));
            *(uint2*)&sL[r][sc4 * 4] = make_uint2((unsigned)l0 | ((unsigned)l1 << 16),
                                                  (unsigned)l2 | ((unsigned)l3 << 16));
        }
        __syncthreads();
        int nxt = tile + GGRID;
        if (nxt < NT) {
#pragma unroll
            for (int i = 0; i < 8; ++i) {
                int gr = nxt * TM + sr + i * 8;
                pf[i] = make_float4(0.f, 0.f, 0.f, 0.f);
                if (gr < N_NODES)
                    pf[i] = *(const float4*)(x + (long long)gr * D + sc4 * 4);
            }
        }

        f32x4 acc[4][2];
#pragma unroll
        for (int m = 0; m < 4; ++m)
#pragma unroll
            for (int tl = 0; tl < 2; ++tl) acc[m][tl] = (f32x4){0.f, 0.f, 0.f, 0.f};

#pragma unroll
        for (int kk = 0; kk < 4; ++kk) {
#pragma unroll
            for (int m = 0; m < 4; ++m) {
                short8 ah = *(const short8*)&sH[m * 16 + lc][kk * 32 + qd * 8];
                short8 al = *(const short8*)&sL[m * 16 + lc][kk * 32 + qd * 8];
#pragma unroll
                for (int tl = 0; tl < 2; ++tl) {
                    acc[m][tl] = __builtin_amdgcn_mfma_f32_16x16x32_bf16(ah, Bh[kk][tl], acc[m][tl], 0, 0, 0);
                    acc[m][tl] = __builtin_amdgcn_mfma_f32_16x16x32_bf16(al, Bh[kk][tl], acc[m][tl], 0, 0, 0);
                    acc[m][tl] = __builtin_amdgcn_mfma_f32_16x16x32_bf16(ah, Bl[kk][tl], acc[m][tl], 0, 0, 0);
                }
            }
        }

        const int row0 = tile * TM;
#pragma unroll
        for (int m = 0; m < 4; ++m)
#pragma unroll
            for (int tl = 0; tl < 2; ++tl) {
                int col = wv * 32 + tl * 16 + lc;
#pragma unroll
                for (int r = 0; r < 4; ++r) {
                    int grow = row0 + m * 16 + qd * 4 + r;
                    if (grow < N_NODES)
                        yh[(long long)grow * D + col] = __float2half(acc[m][tl][r]);
                }
            }
        __syncthreads();
        tile = nxt;
    }
}

// ---------------------------------------------------------------------------
// K3b: per-128-node-bucket: stage slot into LDS, count node degrees, scan,
// write ofs/oen, place adj IN-PLACE over the pairs slot. (sort reverted)
// ---------------------------------------------------------------------------
__launch_bounds__(256)
__global__ void bucket_fill(int* __restrict__ pairs, const int* __restrict__ gcur,
                            int* __restrict__ ofs, int* __restrict__ oen) {
    __shared__ int sP[SLOT];     // 19.2 KB staged edges
    __shared__ int lc[128];
    __shared__ int cur[128];
    const int b    = blockIdx.x;
    const int tid  = threadIdx.x;
    const int base = b * SLOT;
    const int m    = min(gcur[b], SLOT);   // clamp: LDS-overflow guard
    for (int i = tid; i < m; i += 256) sP[i] = pairs[base + i];
    if (tid < 128) lc[tid] = 0;
    __syncthreads();
    for (int i = tid; i < m; i += 256) atomicAdd(&lc[sP[i] >> 17], 1);
    __syncthreads();
    int v = (tid < 128) ? lc[tid] : 0;
    for (int d = 1; d < 128; d <<= 1) {
        int u = (tid >= d && tid < 128) ? lc[tid - d] : 0;
        __syncthreads();
        if (tid < 128) lc[tid] += u;
        __syncthreads();
    }
    if (tid < 128) {
        int abs0 = base + lc[tid] - v;
        cur[tid] = abs0;
        const int n = (b << 7) + tid;
        if (n < N_NODES) { ofs[n] = abs0; oen[n] = abs0 + v; }
    }
    __syncthreads();
    for (int i = tid; i < m; i += 256) {
        int p = sP[i];
        int r = atomicAdd(&cur[p >> 17], 1);
        pairs[r] = p & 0x1FFFF;
    }
}

// ---------------------------------------------------------------------------
// K4: gather-aggregate on y: h1_i = (2+eps)*y_i + sum_nbr y_j + b1.
// 16-deep load pipeline (16 gathers in flight per wave), full-occupancy grid.
// BN stats register-accumulated, block-reduced, flushed to NREP replicas.
// ---------------------------------------------------------------------------
__launch_bounds__(256)
__global__ void gather_aggr(const __half* __restrict__ yh,
                            const int* __restrict__ adj, const int* __restrict__ ofs,
                            const int* __restrict__ oen, const float* __restrict__ eps_p,
                            const float* __restrict__ b1,
                            float* __restrict__ h1, float* __restrict__ stats) {
    const int wv   = threadIdx.x >> 6;
    const int lane = threadIdx.x & 63;
    const int wave = blockIdx.x * 4 + wv;
    const __half2* xp = (const __half2*)yh;
    const float sc = 2.0f + eps_p[0];
    const float2 b1c = ((const float2*)b1)[lane];
    float sx = 0.f, sy = 0.f, qx = 0.f, qy = 0.f;

    for (int node = wave; node < N_NODES; node += GWAVES) {
        int b = ofs[node];
        int e = oen[node];
        float ax = 0.f, ay = 0.f;
        int i = b;
        // 16-deep pipelined main loop: 16 indices, then 16 gathers in flight
        for (; i + 16 <= e; i += 16) {
            int n[16];
#pragma unroll
            for (int j = 0; j < 16; ++j) n[j] = adj[i + j];
            __half2 v[16];
#pragma unroll
            for (int j = 0; j < 16; ++j) v[j] = xp[(unsigned)n[j] * 64u + lane];
#pragma unroll
            for (int j = 0; j < 16; ++j) {
                float2 f = __half22float2(v[j]);
                ax += f.x;
                ay += f.y;
            }
        }
        for (; i + 4 <= e; i += 4) {
            int n0 = adj[i], n1 = adj[i + 1], n2 = adj[i + 2], n3 = adj[i + 3];
            __half2 v0 = xp[(unsigned)n0 * 64u + lane];
            __half2 v1 = xp[(unsigned)n1 * 64u + lane];
            __half2 v2 = xp[(unsigned)n2 * 64u + lane];
            __half2 v3 = xp[(unsigned)n3 * 64u + lane];
            float2 f0 = __half22float2(v0);
            float2 f1 = __half22float2(v1);
            float2 f2 = __half22float2(v2);
            float2 f3 = __half22float2(v3);
            ax += (f0.x + f1.x) + (f2.x + f3.x);
            ay += (f0.y + f1.y) + (f2.y + f3.y);
        }
        for (; i < e; ++i) {
            __half2 v = xp[(unsigned)adj[i] * 64u + lane];
            float2 f = __half22float2(v);
            ax += f.x;
            ay += f.y;
        }
        float2 ys = __half22float2(xp[(unsigned)node * 64u + lane]);
        float ox = fmaf(sc, ys.x, ax) + b1c.x;
        float oy = fmaf(sc, ys.y, ay) + b1c.y;
        ((float2*)h1)[(long long)node * 64 + lane] = make_float2(ox, oy);
        sx += ox; sy += oy;
        qx += ox * ox; qy += oy * oy;
    }

    __shared__ float4 red[4][64];
    red[wv][lane] = make_float4(sx, sy, qx, qy);
    __syncthreads();
    if (wv == 0) {
        float4 a = red[0][lane], b4 = red[1][lane], c = red[2][lane], d4 = red[3][lane];
        float fx = (a.x + b4.x) + (c.x + d4.x);
        float fy = (a.y + b4.y) + (c.y + d4.y);
        float gx = (a.z + b4.z) + (c.z + d4.z);
        float gy = (a.w + b4.w) + (c.w + d4.w);
        float* st = stats + (blockIdx.x & (NREP - 1)) * 256;
        atomicAdd(&st[2 * lane],       fx);
        atomicAdd(&st[2 * lane + 1],   fy);
        atomicAdd(&st[128 + 2 * lane],     gx);
        atomicAdd(&st[128 + 2 * lane + 1], gy);
    }
}

// ---------------------------------------------------------------------------
// K6: out = relu(bn(h1)) @ W2^T + b2  (persistent-B MFMA, W2 split inline,
// grid-strided, prefetch), in-place on d_out. Reduces NREP replicas first.
// ---------------------------------------------------------------------------
__launch_bounds__(256)
__global__ void gemm2_mfma(float* __restrict__ h1out,
                           const float* __restrict__ W2,
                           const float* __restrict__ b2, const float* __restrict__ stats,
                           const float* __restrict__ gamma, const float* __restrict__ beta) {
    __shared__ unsigned short sH[TM][136];
    __shared__ unsigned short sL[TM][136];
    __shared__ float sScale[128];
    __shared__ float sShift[128];
    const int tid = threadIdx.x;
    const int wv  = tid >> 6;
    const int ln  = tid & 63;
    const int lc  = ln & 15;
    const int qd  = ln >> 4;
    const int sr  = tid >> 5;      // staging row base (0..7)
    const int sc4 = tid & 31;      // staging float4 chunk

    if (tid < 128) {
        float s = 0.f, q = 0.f;
#pragma unroll
        for (int r = 0; r < NREP; ++r) {
            s += stats[r * 256 + tid];
            q += stats[r * 256 + 128 + tid];
        }
        float mean = s * (1.0f / N_NODES);
        float var  = fmaxf(q * (1.0f / N_NODES) - mean * mean, 0.0f);
        float sc   = gamma[tid] * rsqrtf(var + BN_EPS);
        sScale[tid] = sc;
        sShift[tid] = beta[tid] - mean * sc;
    }

    short8 Bh[4][2], Bl[4][2];
#pragma unroll
    for (int kk = 0; kk < 4; ++kk)
#pragma unroll
        for (int tl = 0; tl < 2; ++tl) {
            int woff = (wv * 32 + tl * 16 + lc) * D + kk * 32 + qd * 8;
            split8(W2 + woff, &Bh[kk][tl], &Bl[kk][tl]);
        }
    float bb[2];
    bb[0] = b2[wv * 32 + lc];
    bb[1] = b2[wv * 32 + 16 + lc];

    __syncthreads();   // sScale/sShift ready

    float4 pf[8];
    int tile = blockIdx.x;
#pragma unroll
    for (int i = 0; i < 8; ++i) {
        int gr = tile * TM + sr + i * 8;
        pf[i] = make_float4(0.f, 0.f, 0.f, 0.f);
        if (gr < N_NODES)
            pf[i] = *(const float4*)(h1out + (long long)gr * D + sc4 * 4);
    }

    while (tile < NT) {
        float4 scv = *(const float4*)&sScale[sc4 * 4];
        float4 shv = *(const float4*)&sShift[sc4 * 4];
#pragma unroll
        for (int i = 0; i < 8; ++i) {
            int gr = tile * TM + sr + i * 8;
            float4 v = pf[i];
            if (gr < N_NODES) {
                v.x = fmaxf(0.f, fmaf(v.x, scv.x, shv.x));
                v.y = fmaxf(0.f, fmaf(v.y, scv.y, shv.y));
                v.z = fmaxf(0.f, fmaf(v.z, scv.z, shv.z));
                v.w = fmaxf(0.f, fmaf(v.w, scv.w, shv.w));
            } else {
                v = make_float4(0.f, 0.f, 0.f, 0.f);
            }
            unsigned short h0 = bf_hi(v.x), h1b = bf_hi(v.y), h2 = bf_hi(v.z), h3 = bf_hi(v.w);
            unsigned short l0 = bf_hi(v.x - bf_val(h0)), l1 = bf_hi(v.y - bf_val(h1b));
            unsigned short l2 = bf_hi(v.z - bf_val(h2)), l3 = bf_hi(v.w - bf_val(h3));
            int r = sr + i * 8;
            *(uint2*)&sH[r][sc4 * 4] = make_uint2((unsigned)h0 | ((unsigned)h1b << 16),
                                                  (unsigned)h2 | ((unsigned)h3 << 16));
            *(uint2*)&sL[r][sc4 * 4] = make_uint2((unsigned)l0 | ((unsigned)l1 << 16),
                                                  (unsigned)l2 | ((unsigned)l3 << 16));
        }
        __syncthreads();
        int nxt = tile + GGRID;
        if (nxt < NT) {
#pragma unroll
            for (int i = 0; i < 8; ++i) {
                int gr = nxt * TM + sr + i * 8;
                pf[i] = make_float4(0.f, 0.f, 0.f, 0.f);
                if (gr < N_NODES)
                    pf[i] = *(const float4*)(h1out + (long long)gr * D + sc4 * 4);
            }
        }

        f32x4 acc[4][2];
#pragma unroll
        for (int m = 0; m < 4; ++m)
#pragma unroll
            for (int tl = 0; tl < 2; ++tl) acc[m][tl] = (f32x4){0.f, 0.f, 0.f, 0.f};

#pragma unroll
        for (int kk = 0; kk < 4; ++kk) {
#pragma unroll
            for (int m = 0; m < 4; ++m) {
                short8 ah = *(const short8*)&sH[m * 16 + lc][kk * 32 + qd * 8];
                short8 al = *(const short8*)&sL[m * 16 + lc][kk * 32 + qd * 8];
#pragma unroll
                for (int tl = 0; tl < 2; ++tl) {
                    acc[m][tl] = __builtin_amdgcn_mfma_f32_16x16x32_bf16(ah, Bh[kk][tl], acc[m][tl], 0, 0, 0);
                    acc[m][tl] = __builtin_amdgcn_mfma_f32_16x16x32_bf16(al, Bh[kk][tl], acc[m][tl], 0, 0, 0);
                    acc[m][tl] = __builtin_amdgcn_mfma_f32_16x16x32_bf16(ah, Bl[kk][tl], acc[m][tl], 0, 0, 0);
                }
            }
        }

        const int row0 = tile * TM;
#pragma unroll
        for (int m = 0; m < 4; ++m)
#pragma unroll
            for (int tl = 0; tl < 2; ++tl) {
                int col = wv * 32 + tl * 16 + lc;
#pragma unroll
                for (int r = 0; r < 4; ++r) {
                    int grow = row0 + m * 16 + qd * 4 + r;
                    if (grow < N_NODES)
                        h1out[(long long)grow * D + col] = acc[m][tl][r] + bb[tl];
                }
            }
        __syncthreads();
        tile = nxt;
    }
}

// ---------------------------------------------------------------------------
extern "C" void kernel_launch(void* const* d_in, const int* in_sizes, int n_in,
                              void* d_out, int out_size, void* d_ws, size_t ws_size,
                              hipStream_t stream) {
    const float* x     = (const float*)d_in[0];
    const int*   ei    = (const int*)d_in[1];
    const float* eps_p = (const float*)d_in[2];
    const float* W1    = (const float*)d_in[3];
    const float* b1    = (const float*)d_in[4];
    const float* gamma = (const float*)d_in[5];
    const float* beta  = (const float*)d_in[6];
    const float* W2    = (const float*)d_in[7];
    const float* b2    = (const float*)d_in[8];

    // workspace layout (~41.5 MB)
    __half* yh   = (__half*)d_ws;                             // N*128 halfs: y mirror (25.6MB)
    float*  stats = (float*)(yh + (long long)N_NODES * D);    // NREP*256 floats (32KB)
    int*    gcur  = (int*)(stats + NREP * 256);               // 1024 ints (adjacent: one memset)
    int*    ofs   = gcur + 1024;                              // N ints
    int*    oen   = ofs + N_NODES;                            // N ints
    int*    pairs = (int*)(oen + N_NODES);                    // NB*SLOT ints (15.0MB)
    int*    adj   = pairs;                                    // adj aliases pairs (in-place)

    float* out = (float*)d_out;                               // h1 scratch + final out

    // zero stats + gcur (36 KB, graph-capture-safe async memset)
    hipMemsetAsync(stats, 0, (NREP * 256 + 1024) * sizeof(int), stream);

    {   // F1: fused gemm0 (blocks 0..781) + edge partition (blocks 782..1563)
        fused_pg<<<GGRID + 782, 256, 0, stream>>>(x, W1, yh, ei, gcur, pairs);
    }
    {   // K3b: per-bucket LDS-staged count+scan+place -> ofs/oen, adj in-place
        bucket_fill<<<NB, 256, 0, stream>>>(pairs, gcur, ofs, oen);
    }
    {   // K4: 16-deep pipelined gather-aggregate -> h1 (d_out) + BN stats
        gather_aggr<<<GBLKS, 256, 0, stream>>>(yh, adj, ofs, oen, eps_p, b1, out, stats);
    }
    {   // K6: BN finalize + ReLU + persistent-B MFMA GEMM2, in-place on d_out
        gemm2_mfma<<<GGRID, 256, 0, stream>>>(out, W2, b2, stats, gamma, beta);
    }
}

// Round 12
// 334.307 us; speedup vs baseline: 1.0768x; 1.0768x over previous
//
#include <hip/hip_runtime.h>
#include <hip/hip_fp16.h>

#define N_NODES 100000
#define EDGES   1600000
#define D       128
#define BN_EPS  1e-5f
#define TM      64                        // rows per GEMM tile
#define NT      ((N_NODES + TM - 1) / TM) // 1563 row tiles
#define GGRID   782                       // gemm grid-stride: 2 tiles/block
#define NB      782                       // 128-node buckets
#define SLOT    4800                      // per-bucket slot: mean 4092 + 11 sigma
#define L1E     8                         // ei entries per thread (emits 2 pairs each)
#define L1TILE  (256 * L1E)               // 2048 ei entries per tile -> 782 tiles
#define GBLKS   1536                      // gather blocks (proven best: 6/CU)
#define GWAVES  (GBLKS * 4)
#define NREP    32                        // BN-stat replicas

typedef __attribute__((ext_vector_type(8))) short short8;
typedef __attribute__((ext_vector_type(4))) float f32x4;

__device__ __forceinline__ unsigned short bf_hi(float f) {
    unsigned u = __float_as_uint(f);
    unsigned t = u + 0x7FFF + ((u >> 16) & 1);
    return (unsigned short)(t >> 16);
}
__device__ __forceinline__ float bf_val(unsigned short h) {
    return __uint_as_float(((unsigned)h) << 16);
}
// split 8 contiguous fp32 into bf16 hi/lo fragments (for inline W staging)
__device__ __forceinline__ void split8(const float* __restrict__ p, short8* hi, short8* lo) {
    short8 h, l;
#pragma unroll
    for (int i = 0; i < 8; ++i) {
        float f = p[i];
        unsigned short hh = bf_hi(f);
        ((unsigned short*)&h)[i] = (short)hh;
        ((unsigned short*)&l)[i] = (short)bf_hi(f - bf_val(hh));
    }
    *hi = h; *lo = l;
}

// ---------------------------------------------------------------------------
// F1: heterogeneous fused kernel.
//   blocks [0, GGRID)          : gemm0  y = x @ W1^T -> fp16 mirror (W1 split inline)
//   blocks [GGRID, GGRID+782)  : edge partition into 128-node buckets
// pairs entry: (local_dst<<17) | src   (local_dst < 128, src < 2^17)
// ---------------------------------------------------------------------------
__launch_bounds__(256)
__global__ void fused_pg(const float* __restrict__ x,
                         const float* __restrict__ W1,
                         __half* __restrict__ yh,
                         const int* __restrict__ ei, int* __restrict__ gcur,
                         int* __restrict__ pairs) {
    __shared__ unsigned short sH[TM][136];
    __shared__ unsigned short sL[TM][136];
    const int tid = threadIdx.x;

    if (blockIdx.x >= GGRID) {
        // ---------------- partition path ----------------
        int* cnt   = (int*)&sH[0][0];        // 782 ints
        int* cbase = cnt + NB;               // 782 ints  (6.3 KB total, aliased)
        for (int i = tid; i < NB; i += 256) cnt[i] = 0;
        __syncthreads();

        int bbA[L1E], rrA[L1E], pkA[L1E];
        int bbB[L1E], rrB[L1E], pkB[L1E];
        const int t0 = (blockIdx.x - GGRID) * L1TILE + tid;
#pragma unroll
        for (int j = 0; j < L1E; ++j) {
            int t = t0 + j * 256;
            bbA[j] = -1;
            bbB[j] = -1;
            if (t < EDGES) {
                int s = ei[t];
                int d = ei[EDGES + t];
                bbA[j] = d >> 7;                     // aggr[d] += y[s]
                pkA[j] = ((d & 127) << 17) | s;
                rrA[j] = atomicAdd(&cnt[bbA[j]], 1);
                bbB[j] = s >> 7;                     // aggr[s] += y[d]
                pkB[j] = ((s & 127) << 17) | d;
                rrB[j] = atomicAdd(&cnt[bbB[j]], 1);
            }
        }
        __syncthreads();
        for (int i = tid; i < NB; i += 256) {
            int c = cnt[i];
            cbase[i] = c ? (i * SLOT + atomicAdd(&gcur[i], c)) : 0;
        }
        __syncthreads();
#pragma unroll
        for (int j = 0; j < L1E; ++j) {
            if (bbA[j] >= 0) {
                pairs[cbase[bbA[j]] + rrA[j]] = pkA[j];
                pairs[cbase[bbB[j]] + rrB[j]] = pkB[j];
            }
        }
        return;
    }

    // ---------------- gemm0 path ----------------
    const int wv  = tid >> 6;
    const int ln  = tid & 63;
    const int lc  = ln & 15;
    const int qd  = ln >> 4;
    const int sr  = tid >> 5;      // staging row base (0..7)
    const int sc4 = tid & 31;      // staging float4 chunk

    short8 Bh[4][2], Bl[4][2];
#pragma unroll
    for (int kk = 0; kk < 4; ++kk)
#pragma unroll
        for (int tl = 0; tl < 2; ++tl) {
            int woff = (wv * 32 + tl * 16 + lc) * D + kk * 32 + qd * 8;
            split8(W1 + woff, &Bh[kk][tl], &Bl[kk][tl]);
        }

    float4 pf[8];
    int tile = blockIdx.x;
#pragma unroll
    for (int i = 0; i < 8; ++i) {
        int gr = tile * TM + sr + i * 8;
        pf[i] = make_float4(0.f, 0.f, 0.f, 0.f);
        if (gr < N_NODES)
            pf[i] = *(const float4*)(x + (long long)gr * D + sc4 * 4);
    }

    while (tile < NT) {
#pragma unroll
        for (int i = 0; i < 8; ++i) {
            float4 v = pf[i];
            unsigned short h0 = bf_hi(v.x), h1b = bf_hi(v.y), h2 = bf_hi(v.z), h3 = bf_hi(v.w);
            unsigned short l0 = bf_hi(v.x - bf_val(h0)), l1 = bf_hi(v.y - bf_val(h1b));
            unsigned short l2 = bf_hi(v.z - bf_val(h2)), l3 = bf_hi(v.w - bf_val(h3));
            int r = sr + i * 8;
            *(uint2*)&sH[r][sc4 * 4] = make_uint2((unsigned)h0 | ((unsigned)h1b << 16),
                                                  (unsigned)h2 | ((unsigned)h3 << 16));
            *(uint2*)&sL[r][sc4 * 4] = make_uint2((unsigned)l0 | ((unsigned)l1 << 16),
                                                  (unsigned)l2 | ((unsigned)l3 << 16));
        }
        __syncthreads();
        int nxt = tile + GGRID;
        if (nxt < NT) {
#pragma unroll
            for (int i = 0; i < 8; ++i) {
                int gr = nxt * TM + sr + i * 8;
                pf[i] = make_float4(0.f, 0.f, 0.f, 0.f);
                if (gr < N_NODES)
                    pf[i] = *(const float4*)(x + (long long)gr * D + sc4 * 4);
            }
        }

        f32x4 acc[4][2];
#pragma unroll
        for (int m = 0; m < 4; ++m)
#pragma unroll
            for (int tl = 0; tl < 2; ++tl) acc[m][tl] = (f32x4){0.f, 0.f, 0.f, 0.f};

#pragma unroll
        for (int kk = 0; kk < 4; ++kk) {
#pragma unroll
            for (int m = 0; m < 4; ++m) {
                short8 ah = *(const short8*)&sH[m * 16 + lc][kk * 32 + qd * 8];
                short8 al = *(const short8*)&sL[m * 16 + lc][kk * 32 + qd * 8];
#pragma unroll
                for (int tl = 0; tl < 2; ++tl) {
                    acc[m][tl] = __builtin_amdgcn_mfma_f32_16x16x32_bf16(ah, Bh[kk][tl], acc[m][tl], 0, 0, 0);
                    acc[m][tl] = __builtin_amdgcn_mfma_f32_16x16x32_bf16(al, Bh[kk][tl], acc[m][tl], 0, 0, 0);
                    acc[m][tl] = __builtin_amdgcn_mfma_f32_16x16x32_bf16(ah, Bl[kk][tl], acc[m][tl], 0, 0, 0);
                }
            }
        }

        const int row0 = tile * TM;
#pragma unroll
        for (int m = 0; m < 4; ++m)
#pragma unroll
            for (int tl = 0; tl < 2; ++tl) {
                int col = wv * 32 + tl * 16 + lc;
#pragma unroll
                for (int r = 0; r < 4; ++r) {
                    int grow = row0 + m * 16 + qd * 4 + r;
                    if (grow < N_NODES)
                        yh[(long long)grow * D + col] = __float2half(acc[m][tl][r]);
                }
            }
        __syncthreads();
        tile = nxt;
    }
}

// ---------------------------------------------------------------------------
// K3b: per-128-node-bucket: stage slot into LDS, count node degrees, scan,
// write ofs/oen, place adj IN-PLACE over the pairs slot.
// ---------------------------------------------------------------------------
__launch_bounds__(256)
__global__ void bucket_fill(int* __restrict__ pairs, const int* __restrict__ gcur,
                            int* __restrict__ ofs, int* __restrict__ oen) {
    __shared__ int sP[SLOT];     // 19.2 KB staged edges
    __shared__ int lc[128];
    __shared__ int cur[128];
    const int b    = blockIdx.x;
    const int tid  = threadIdx.x;
    const int base = b * SLOT;
    const int m    = min(gcur[b], SLOT);   // clamp: LDS-overflow guard
    for (int i = tid; i < m; i += 256) sP[i] = pairs[base + i];
    if (tid < 128) lc[tid] = 0;
    __syncthreads();
    for (int i = tid; i < m; i += 256) atomicAdd(&lc[sP[i] >> 17], 1);
    __syncthreads();
    int v = (tid < 128) ? lc[tid] : 0;
    for (int d = 1; d < 128; d <<= 1) {
        int u = (tid >= d && tid < 128) ? lc[tid - d] : 0;
        __syncthreads();
        if (tid < 128) lc[tid] += u;
        __syncthreads();
    }
    if (tid < 128) {
        int abs0 = base + lc[tid] - v;
        cur[tid] = abs0;
        const int n = (b << 7) + tid;
        if (n < N_NODES) { ofs[n] = abs0; oen[n] = abs0 + v; }
    }
    __syncthreads();
    for (int i = tid; i < m; i += 256) {
        int p = sP[i];
        int r = atomicAdd(&cur[p >> 17], 1);
        pairs[r] = p & 0x1FFFF;
    }
}

// ---------------------------------------------------------------------------
// K4: gather-aggregate on y: h1_i = (2+eps)*y_i + sum_nbr y_j + b1.
// Persistent grid-stride (node per wave, 8-deep pipeline — proven config);
// BN stats register-accumulated, block-reduced, flushed to NREP replicas.
// ---------------------------------------------------------------------------
__launch_bounds__(256)
__global__ void gather_aggr(const __half* __restrict__ yh,
                            const int* __restrict__ adj, const int* __restrict__ ofs,
                            const int* __restrict__ oen, const float* __restrict__ eps_p,
                            const float* __restrict__ b1,
                            float* __restrict__ h1, float* __restrict__ stats) {
    const int wv   = threadIdx.x >> 6;
    const int lane = threadIdx.x & 63;
    const int wave = blockIdx.x * 4 + wv;
    const __half2* xp = (const __half2*)yh;
    const float sc = 2.0f + eps_p[0];
    const float2 b1c = ((const float2*)b1)[lane];
    float sx = 0.f, sy = 0.f, qx = 0.f, qy = 0.f;

    for (int node = wave; node < N_NODES; node += GWAVES) {
        int b = ofs[node];
        int e = oen[node];
        float ax = 0.f, ay = 0.f;
        int i = b;
        for (; i + 8 <= e; i += 8) {
            int n0 = adj[i],     n1 = adj[i + 1], n2 = adj[i + 2], n3 = adj[i + 3];
            int n4 = adj[i + 4], n5 = adj[i + 5], n6 = adj[i + 6], n7 = adj[i + 7];
            __half2 v0 = xp[(unsigned)n0 * 64u + lane];
            __half2 v1 = xp[(unsigned)n1 * 64u + lane];
            __half2 v2 = xp[(unsigned)n2 * 64u + lane];
            __half2 v3 = xp[(unsigned)n3 * 64u + lane];
            __half2 v4 = xp[(unsigned)n4 * 64u + lane];
            __half2 v5 = xp[(unsigned)n5 * 64u + lane];
            __half2 v6 = xp[(unsigned)n6 * 64u + lane];
            __half2 v7 = xp[(unsigned)n7 * 64u + lane];
            float2 f0 = __half22float2(v0);
            float2 f1 = __half22float2(v1);
            float2 f2 = __half22float2(v2);
            float2 f3 = __half22float2(v3);
            float2 f4 = __half22float2(v4);
            float2 f5 = __half22float2(v5);
            float2 f6 = __half22float2(v6);
            float2 f7 = __half22float2(v7);
            ax += ((f0.x + f1.x) + (f2.x + f3.x)) + ((f4.x + f5.x) + (f6.x + f7.x));
            ay += ((f0.y + f1.y) + (f2.y + f3.y)) + ((f4.y + f5.y) + (f6.y + f7.y));
        }
        for (; i + 4 <= e; i += 4) {
            int n0 = adj[i], n1 = adj[i + 1], n2 = adj[i + 2], n3 = adj[i + 3];
            __half2 v0 = xp[(unsigned)n0 * 64u + lane];
            __half2 v1 = xp[(unsigned)n1 * 64u + lane];
            __half2 v2 = xp[(unsigned)n2 * 64u + lane];
            __half2 v3 = xp[(unsigned)n3 * 64u + lane];
            float2 f0 = __half22float2(v0);
            float2 f1 = __half22float2(v1);
            float2 f2 = __half22float2(v2);
            float2 f3 = __half22float2(v3);
            ax += (f0.x + f1.x) + (f2.x + f3.x);
            ay += (f0.y + f1.y) + (f2.y + f3.y);
        }
        for (; i < e; ++i) {
            __half2 v = xp[(unsigned)adj[i] * 64u + lane];
            float2 f = __half22float2(v);
            ax += f.x;
            ay += f.y;
        }
        float2 ys = __half22float2(xp[(unsigned)node * 64u + lane]);
        float ox = fmaf(sc, ys.x, ax) + b1c.x;
        float oy = fmaf(sc, ys.y, ay) + b1c.y;
        ((float2*)h1)[(long long)node * 64 + lane] = make_float2(ox, oy);
        sx += ox; sy += oy;
        qx += ox * ox; qy += oy * oy;
    }

    __shared__ float4 red[4][64];
    red[wv][lane] = make_float4(sx, sy, qx, qy);
    __syncthreads();
    if (wv == 0) {
        float4 a = red[0][lane], b4 = red[1][lane], c = red[2][lane], d4 = red[3][lane];
        float fx = (a.x + b4.x) + (c.x + d4.x);
        float fy = (a.y + b4.y) + (c.y + d4.y);
        float gx = (a.z + b4.z) + (c.z + d4.z);
        float gy = (a.w + b4.w) + (c.w + d4.w);
        float* st = stats + (blockIdx.x & (NREP - 1)) * 256;
        atomicAdd(&st[2 * lane],       fx);
        atomicAdd(&st[2 * lane + 1],   fy);
        atomicAdd(&st[128 + 2 * lane],     gx);
        atomicAdd(&st[128 + 2 * lane + 1], gy);
    }
}

// ---------------------------------------------------------------------------
// K6: out = relu(bn(h1)) @ W2^T + b2  (persistent-B MFMA, W2 split inline,
// grid-strided, prefetch), in-place on d_out. Reduces NREP replicas first.
// ---------------------------------------------------------------------------
__launch_bounds__(256)
__global__ void gemm2_mfma(float* __restrict__ h1out,
                           const float* __restrict__ W2,
                           const float* __restrict__ b2, const float* __restrict__ stats,
                           const float* __restrict__ gamma, const float* __restrict__ beta) {
    __shared__ unsigned short sH[TM][136];
    __shared__ unsigned short sL[TM][136];
    __shared__ float sScale[128];
    __shared__ float sShift[128];
    const int tid = threadIdx.x;
    const int wv  = tid >> 6;
    const int ln  = tid & 63;
    const int lc  = ln & 15;
    const int qd  = ln >> 4;
    const int sr  = tid >> 5;      // staging row base (0..7)
    const int sc4 = tid & 31;      // staging float4 chunk

    if (tid < 128) {
        float s = 0.f, q = 0.f;
#pragma unroll
        for (int r = 0; r < NREP; ++r) {
            s += stats[r * 256 + tid];
            q += stats[r * 256 + 128 + tid];
        }
        float mean = s * (1.0f / N_NODES);
        float var  = fmaxf(q * (1.0f / N_NODES) - mean * mean, 0.0f);
        float sc   = gamma[tid] * rsqrtf(var + BN_EPS);
        sScale[tid] = sc;
        sShift[tid] = beta[tid] - mean * sc;
    }

    short8 Bh[4][2], Bl[4][2];
#pragma unroll
    for (int kk = 0; kk < 4; ++kk)
#pragma unroll
        for (int tl = 0; tl < 2; ++tl) {
            int woff = (wv * 32 + tl * 16 + lc) * D + kk * 32 + qd * 8;
            split8(W2 + woff, &Bh[kk][tl], &Bl[kk][tl]);
        }
    float bb[2];
    bb[0] = b2[wv * 32 + lc];
    bb[1] = b2[wv * 32 + 16 + lc];

    __syncthreads();   // sScale/sShift ready

    float4 pf[8];
    int tile = blockIdx.x;
#pragma unroll
    for (int i = 0; i < 8; ++i) {
        int gr = tile * TM + sr + i * 8;
        pf[i] = make_float4(0.f, 0.f, 0.f, 0.f);
        if (gr < N_NODES)
            pf[i] = *(const float4*)(h1out + (long long)gr * D + sc4 * 4);
    }

    while (tile < NT) {
        float4 scv = *(const float4*)&sScale[sc4 * 4];
        float4 shv = *(const float4*)&sShift[sc4 * 4];
#pragma unroll
        for (int i = 0; i < 8; ++i) {
            int gr = tile * TM + sr + i * 8;
            float4 v = pf[i];
            if (gr < N_NODES) {
                v.x = fmaxf(0.f, fmaf(v.x, scv.x, shv.x));
                v.y = fmaxf(0.f, fmaf(v.y, scv.y, shv.y));
                v.z = fmaxf(0.f, fmaf(v.z, scv.z, shv.z));
                v.w = fmaxf(0.f, fmaf(v.w, scv.w, shv.w));
            } else {
                v = make_float4(0.f, 0.f, 0.f, 0.f);
            }
            unsigned short h0 = bf_hi(v.x), h1b = bf_hi(v.y), h2 = bf_hi(v.z), h3 = bf_hi(v.w);
            unsigned short l0 = bf_hi(v.x - bf_val(h0)), l1 = bf_hi(v.y - bf_val(h1b));
            unsigned short l2 = bf_hi(v.z - bf_val(h2)), l3 = bf_hi(v.w - bf_val(h3));
            int r = sr + i * 8;
            *(uint2*)&sH[r][sc4 * 4] = make_uint2((unsigned)h0 | ((unsigned)h1b << 16),
                                                  (unsigned)h2 | ((unsigned)h3 << 16));
            *(uint2*)&sL[r][sc4 * 4] = make_uint2((unsigned)l0 | ((unsigned)l1 << 16),
                                                  (unsigned)l2 | ((unsigned)l3 << 16));
        }
        __syncthreads();
        int nxt = tile + GGRID;
        if (nxt < NT) {
#pragma unroll
            for (int i = 0; i < 8; ++i) {
                int gr = nxt * TM + sr + i * 8;
                pf[i] = make_float4(0.f, 0.f, 0.f, 0.f);
                if (gr < N_NODES)
                    pf[i] = *(const float4*)(h1out + (long long)gr * D + sc4 * 4);
            }
        }

        f32x4 acc[4][2];
#pragma unroll
        for (int m = 0; m < 4; ++m)
#pragma unroll
            for (int tl = 0; tl < 2; ++tl) acc[m][tl] = (f32x4){0.f, 0.f, 0.f, 0.f};

#pragma unroll
        for (int kk = 0; kk < 4; ++kk) {
#pragma unroll
            for (int m = 0; m < 4; ++m) {
                short8 ah = *(const short8*)&sH[m * 16 + lc][kk * 32 + qd * 8];
                short8 al = *(const short8*)&sL[m * 16 + lc][kk * 32 + qd * 8];
#pragma unroll
                for (int tl = 0; tl < 2; ++tl) {
                    acc[m][tl] = __builtin_amdgcn_mfma_f32_16x16x32_bf16(ah, Bh[kk][tl], acc[m][tl], 0, 0, 0);
                    acc[m][tl] = __builtin_amdgcn_mfma_f32_16x16x32_bf16(al, Bh[kk][tl], acc[m][tl], 0, 0, 0);
                    acc[m][tl] = __builtin_amdgcn_mfma_f32_16x16x32_bf16(ah, Bl[kk][tl], acc[m][tl], 0, 0, 0);
                }
            }
        }

        const int row0 = tile * TM;
#pragma unroll
        for (int m = 0; m < 4; ++m)
#pragma unroll
            for (int tl = 0; tl < 2; ++tl) {
                int col = wv * 32 + tl * 16 + lc;
#pragma unroll
                for (int r = 0; r < 4; ++r) {
                    int grow = row0 + m * 16 + qd * 4 + r;
                    if (grow < N_NODES)
                        h1out[(long long)grow * D + col] = acc[m][tl][r] + bb[tl];
                }
            }
        __syncthreads();
        tile = nxt;
    }
}

// ---------------------------------------------------------------------------
extern "C" void kernel_launch(void* const* d_in, const int* in_sizes, int n_in,
                              void* d_out, int out_size, void* d_ws, size_t ws_size,
                              hipStream_t stream) {
    const float* x     = (const float*)d_in[0];
    const int*   ei    = (const int*)d_in[1];
    const float* eps_p = (const float*)d_in[2];
    const float* W1    = (const float*)d_in[3];
    const float* b1    = (const float*)d_in[4];
    const float* gamma = (const float*)d_in[5];
    const float* beta  = (const float*)d_in[6];
    const float* W2    = (const float*)d_in[7];
    const float* b2    = (const float*)d_in[8];

    // workspace layout (~41.5 MB)
    __half* yh   = (__half*)d_ws;                             // N*128 halfs: y mirror (25.6MB)
    float*  stats = (float*)(yh + (long long)N_NODES * D);    // NREP*256 floats (32KB)
    int*    gcur  = (int*)(stats + NREP * 256);               // 1024 ints (adjacent: one memset)
    int*    ofs   = gcur + 1024;                              // N ints
    int*    oen   = ofs + N_NODES;                            // N ints
    int*    pairs = (int*)(oen + N_NODES);                    // NB*SLOT ints (15.0MB)
    int*    adj   = pairs;                                    // adj aliases pairs (in-place)

    float* out = (float*)d_out;                               // h1 scratch + final out

    // zero stats + gcur (36 KB, graph-capture-safe async memset)
    hipMemsetAsync(stats, 0, (NREP * 256 + 1024) * sizeof(int), stream);

    {   // F1: fused gemm0 (blocks 0..781) + edge partition (blocks 782..1563)
        fused_pg<<<GGRID + 782, 256, 0, stream>>>(x, W1, yh, ei, gcur, pairs);
    }
    {   // K3b: per-bucket LDS-staged count+scan+place -> ofs/oen, adj in-place
        bucket_fill<<<NB, 256, 0, stream>>>(pairs, gcur, ofs, oen);
    }
    {   // K4: gather-aggregate (8-deep pipeline) -> h1 (d_out) + BN stats
        gather_aggr<<<GBLKS, 256, 0, stream>>>(yh, adj, ofs, oen, eps_p, b1, out, stats);
    }
    {   // K6: BN finalize + ReLU + persistent-B MFMA GEMM2, in-place on d_out
        gemm2_mfma<<<GGRID, 256, 0, stream>>>(out, W2, b2, stats, gamma, beta);
    }
}

// Round 13
// 324.018 us; speedup vs baseline: 1.1110x; 1.0318x over previous
//
#include <hip/hip_runtime.h>
#include <hip/hip_fp16.h>

#define N_NODES 100000
#define EDGES   1600000
#define D       128
#define BN_EPS  1e-5f
#define TM      64                        // rows per GEMM tile
#define NT      ((N_NODES + TM - 1) / TM) // 1563 row tiles
#define GGRID   782                       // gemm grid-stride: 2 tiles/block
#define NB      782                       // 128-node buckets
#define SLOT    4800                      // per-bucket slot: mean 4092 + 11 sigma
#define L1E     8                         // ei entries per thread (emits 2 pairs each)
#define L1TILE  (256 * L1E)               // 2048 ei entries per tile -> 782 tiles
#define NREP    32                        // BN-stat replicas

typedef __attribute__((ext_vector_type(8))) short short8;
typedef __attribute__((ext_vector_type(4))) float f32x4;

__device__ __forceinline__ unsigned short bf_hi(float f) {
    unsigned u = __float_as_uint(f);
    unsigned t = u + 0x7FFF + ((u >> 16) & 1);
    return (unsigned short)(t >> 16);
}
__device__ __forceinline__ float bf_val(unsigned short h) {
    return __uint_as_float(((unsigned)h) << 16);
}
// split 8 contiguous fp32 into bf16 hi/lo fragments (for inline W staging)
__device__ __forceinline__ void split8(const float* __restrict__ p, short8* hi, short8* lo) {
    short8 h, l;
#pragma unroll
    for (int i = 0; i < 8; ++i) {
        float f = p[i];
        unsigned short hh = bf_hi(f);
        ((unsigned short*)&h)[i] = (short)hh;
        ((unsigned short*)&l)[i] = (short)bf_hi(f - bf_val(hh));
    }
    *hi = h; *lo = l;
}

// ---------------------------------------------------------------------------
// F1: heterogeneous fused kernel.
//   blocks [0, GGRID)          : gemm0  y = x @ W1^T -> fp16 mirror (W1 split inline)
//   blocks [GGRID, GGRID+782)  : edge partition into 128-node buckets
// pairs entry: (local_dst<<17) | src   (local_dst < 128, src < 2^17)
// ---------------------------------------------------------------------------
__launch_bounds__(256)
__global__ void fused_pg(const float* __restrict__ x,
                         const float* __restrict__ W1,
                         __half* __restrict__ yh,
                         const int* __restrict__ ei, int* __restrict__ gcur,
                         int* __restrict__ pairs) {
    __shared__ unsigned short sH[TM][136];
    __shared__ unsigned short sL[TM][136];
    const int tid = threadIdx.x;

    if (blockIdx.x >= GGRID) {
        // ---------------- partition path ----------------
        int* cnt   = (int*)&sH[0][0];        // 782 ints
        int* cbase = cnt + NB;               // 782 ints  (6.3 KB total, aliased)
        for (int i = tid; i < NB; i += 256) cnt[i] = 0;
        __syncthreads();

        int bbA[L1E], rrA[L1E], pkA[L1E];
        int bbB[L1E], rrB[L1E], pkB[L1E];
        const int t0 = (blockIdx.x - GGRID) * L1TILE + tid;
#pragma unroll
        for (int j = 0; j < L1E; ++j) {
            int t = t0 + j * 256;
            bbA[j] = -1;
            bbB[j] = -1;
            if (t < EDGES) {
                int s = ei[t];
                int d = ei[EDGES + t];
                bbA[j] = d >> 7;                     // aggr[d] += y[s]
                pkA[j] = ((d & 127) << 17) | s;
                rrA[j] = atomicAdd(&cnt[bbA[j]], 1);
                bbB[j] = s >> 7;                     // aggr[s] += y[d]
                pkB[j] = ((s & 127) << 17) | d;
                rrB[j] = atomicAdd(&cnt[bbB[j]], 1);
            }
        }
        __syncthreads();
        for (int i = tid; i < NB; i += 256) {
            int c = cnt[i];
            cbase[i] = c ? (i * SLOT + atomicAdd(&gcur[i], c)) : 0;
        }
        __syncthreads();
#pragma unroll
        for (int j = 0; j < L1E; ++j) {
            if (bbA[j] >= 0) {
                pairs[cbase[bbA[j]] + rrA[j]] = pkA[j];
                pairs[cbase[bbB[j]] + rrB[j]] = pkB[j];
            }
        }
        return;
    }

    // ---------------- gemm0 path ----------------
    const int wv  = tid >> 6;
    const int ln  = tid & 63;
    const int lc  = ln & 15;
    const int qd  = ln >> 4;
    const int sr  = tid >> 5;      // staging row base (0..7)
    const int sc4 = tid & 31;      // staging float4 chunk

    short8 Bh[4][2], Bl[4][2];
#pragma unroll
    for (int kk = 0; kk < 4; ++kk)
#pragma unroll
        for (int tl = 0; tl < 2; ++tl) {
            int woff = (wv * 32 + tl * 16 + lc) * D + kk * 32 + qd * 8;
            split8(W1 + woff, &Bh[kk][tl], &Bl[kk][tl]);
        }

    float4 pf[8];
    int tile = blockIdx.x;
#pragma unroll
    for (int i = 0; i < 8; ++i) {
        int gr = tile * TM + sr + i * 8;
        pf[i] = make_float4(0.f, 0.f, 0.f, 0.f);
        if (gr < N_NODES)
            pf[i] = *(const float4*)(x + (long long)gr * D + sc4 * 4);
    }

    while (tile < NT) {
#pragma unroll
        for (int i = 0; i < 8; ++i) {
            float4 v = pf[i];
            unsigned short h0 = bf_hi(v.x), h1b = bf_hi(v.y), h2 = bf_hi(v.z), h3 = bf_hi(v.w);
            unsigned short l0 = bf_hi(v.x - bf_val(h0)), l1 = bf_hi(v.y - bf_val(h1b));
            unsigned short l2 = bf_hi(v.z - bf_val(h2)), l3 = bf_hi(v.w - bf_val(h3));
            int r = sr + i * 8;
            *(uint2*)&sH[r][sc4 * 4] = make_uint2((unsigned)h0 | ((unsigned)h1b << 16),
                                                  (unsigned)h2 | ((unsigned)h3 << 16));
            *(uint2*)&sL[r][sc4 * 4] = make_uint2((unsigned)l0 | ((unsigned)l1 << 16),
                                                  (unsigned)l2 | ((unsigned)l3 << 16));
        }
        __syncthreads();
        int nxt = tile + GGRID;
        if (nxt < NT) {
#pragma unroll
            for (int i = 0; i < 8; ++i) {
                int gr = nxt * TM + sr + i * 8;
                pf[i] = make_float4(0.f, 0.f, 0.f, 0.f);
                if (gr < N_NODES)
                    pf[i] = *(const float4*)(x + (long long)gr * D + sc4 * 4);
            }
        }

        f32x4 acc[4][2];
#pragma unroll
        for (int m = 0; m < 4; ++m)
#pragma unroll
            for (int tl = 0; tl < 2; ++tl) acc[m][tl] = (f32x4){0.f, 0.f, 0.f, 0.f};

#pragma unroll
        for (int kk = 0; kk < 4; ++kk) {
#pragma unroll
            for (int m = 0; m < 4; ++m) {
                short8 ah = *(const short8*)&sH[m * 16 + lc][kk * 32 + qd * 8];
                short8 al = *(const short8*)&sL[m * 16 + lc][kk * 32 + qd * 8];
#pragma unroll
                for (int tl = 0; tl < 2; ++tl) {
                    acc[m][tl] = __builtin_amdgcn_mfma_f32_16x16x32_bf16(ah, Bh[kk][tl], acc[m][tl], 0, 0, 0);
                    acc[m][tl] = __builtin_amdgcn_mfma_f32_16x16x32_bf16(al, Bh[kk][tl], acc[m][tl], 0, 0, 0);
                    acc[m][tl] = __builtin_amdgcn_mfma_f32_16x16x32_bf16(ah, Bl[kk][tl], acc[m][tl], 0, 0, 0);
                }
            }
        }

        const int row0 = tile * TM;
#pragma unroll
        for (int m = 0; m < 4; ++m)
#pragma unroll
            for (int tl = 0; tl < 2; ++tl) {
                int col = wv * 32 + tl * 16 + lc;
#pragma unroll
                for (int r = 0; r < 4; ++r) {
                    int grow = row0 + m * 16 + qd * 4 + r;
                    if (grow < N_NODES)
                        yh[(long long)grow * D + col] = __float2half(acc[m][tl][r]);
                }
            }
        __syncthreads();
        tile = nxt;
    }
}

// ---------------------------------------------------------------------------
// K4: fused bucket-build + gather. One block per 128-node bucket (512 thr,
// 8 waves). Prologue: read pairs slot into registers (static idx), degree
// count + scan + place sorted adj in LDS. Gather phase: 16 nodes/wave,
// 8-deep pipeline, adj from LDS. BN stats -> NREP replicas.
// ---------------------------------------------------------------------------
__launch_bounds__(512)
__global__ void bucket_gather(const __half* __restrict__ yh,
                              const int* __restrict__ pairs, const int* __restrict__ gcur,
                              const float* __restrict__ eps_p, const float* __restrict__ b1,
                              float* __restrict__ h1, float* __restrict__ stats) {
    __shared__ int sA[SLOT];        // 19.2 KB: sorted adjacency (src ids)
    __shared__ int lc[128];
    __shared__ int cur[128];
    __shared__ int nofs[129];
    __shared__ float4 red[8][64];   // 8 KB
    const int b    = blockIdx.x;
    const int tid  = threadIdx.x;
    const int base = b * SLOT;
    const int m    = min(gcur[b], SLOT);

    // prologue: slot -> registers (statically indexed), count, scan, place
    int my[10];
#pragma unroll
    for (int k = 0; k < 10; ++k) {
        int i = tid + k * 512;
        my[k] = (i < m) ? pairs[base + i] : -1;
    }
    if (tid < 128) lc[tid] = 0;
    __syncthreads();
#pragma unroll
    for (int k = 0; k < 10; ++k)
        if (my[k] >= 0) atomicAdd(&lc[my[k] >> 17], 1);
    __syncthreads();
    int v = (tid < 128) ? lc[tid] : 0;
    for (int d = 1; d < 128; d <<= 1) {
        int u = (tid >= d && tid < 128) ? lc[tid - d] : 0;
        __syncthreads();
        if (tid < 128) lc[tid] += u;
        __syncthreads();
    }
    if (tid < 128) {
        int e0 = lc[tid] - v;          // exclusive scan, 0-based in bucket
        cur[tid]  = e0;
        nofs[tid] = e0;
        if (tid == 127) nofs[128] = lc[127];
    }
    __syncthreads();
#pragma unroll
    for (int k = 0; k < 10; ++k)
        if (my[k] >= 0) {
            int r = atomicAdd(&cur[my[k] >> 17], 1);
            sA[r] = my[k] & 0x1FFFF;
        }
    __syncthreads();

    // gather phase
    const int wv   = tid >> 6;      // 0..7
    const int lane = tid & 63;
    const __half2* xp = (const __half2*)yh;
    const float sc = 2.0f + eps_p[0];
    const float2 b1c = ((const float2*)b1)[lane];
    float sx = 0.f, sy = 0.f, qx = 0.f, qy = 0.f;

    for (int ln = wv * 16; ln < wv * 16 + 16; ++ln) {
        int node = (b << 7) + ln;
        if (node >= N_NODES) break;
        int nb = nofs[ln];
        int ne = nofs[ln + 1];
        float ax = 0.f, ay = 0.f;
        int i = nb;
        for (; i + 8 <= ne; i += 8) {
            int n0 = sA[i],     n1 = sA[i + 1], n2 = sA[i + 2], n3 = sA[i + 3];
            int n4 = sA[i + 4], n5 = sA[i + 5], n6 = sA[i + 6], n7 = sA[i + 7];
            __half2 v0 = xp[(unsigned)n0 * 64u + lane];
            __half2 v1 = xp[(unsigned)n1 * 64u + lane];
            __half2 v2 = xp[(unsigned)n2 * 64u + lane];
            __half2 v3 = xp[(unsigned)n3 * 64u + lane];
            __half2 v4 = xp[(unsigned)n4 * 64u + lane];
            __half2 v5 = xp[(unsigned)n5 * 64u + lane];
            __half2 v6 = xp[(unsigned)n6 * 64u + lane];
            __half2 v7 = xp[(unsigned)n7 * 64u + lane];
            float2 f0 = __half22float2(v0);
            float2 f1 = __half22float2(v1);
            float2 f2 = __half22float2(v2);
            float2 f3 = __half22float2(v3);
            float2 f4 = __half22float2(v4);
            float2 f5 = __half22float2(v5);
            float2 f6 = __half22float2(v6);
            float2 f7 = __half22float2(v7);
            ax += ((f0.x + f1.x) + (f2.x + f3.x)) + ((f4.x + f5.x) + (f6.x + f7.x));
            ay += ((f0.y + f1.y) + (f2.y + f3.y)) + ((f4.y + f5.y) + (f6.y + f7.y));
        }
        for (; i + 4 <= ne; i += 4) {
            int n0 = sA[i], n1 = sA[i + 1], n2 = sA[i + 2], n3 = sA[i + 3];
            __half2 v0 = xp[(unsigned)n0 * 64u + lane];
            __half2 v1 = xp[(unsigned)n1 * 64u + lane];
            __half2 v2 = xp[(unsigned)n2 * 64u + lane];
            __half2 v3 = xp[(unsigned)n3 * 64u + lane];
            float2 f0 = __half22float2(v0);
            float2 f1 = __half22float2(v1);
            float2 f2 = __half22float2(v2);
            float2 f3 = __half22float2(v3);
            ax += (f0.x + f1.x) + (f2.x + f3.x);
            ay += (f0.y + f1.y) + (f2.y + f3.y);
        }
        for (; i < ne; ++i) {
            __half2 vv = xp[(unsigned)sA[i] * 64u + lane];
            float2 f = __half22float2(vv);
            ax += f.x;
            ay += f.y;
        }
        float2 ys = __half22float2(xp[(unsigned)node * 64u + lane]);
        float ox = fmaf(sc, ys.x, ax) + b1c.x;
        float oy = fmaf(sc, ys.y, ay) + b1c.y;
        ((float2*)h1)[(long long)node * 64 + lane] = make_float2(ox, oy);
        sx += ox; sy += oy;
        qx += ox * ox; qy += oy * oy;
    }

    red[wv][lane] = make_float4(sx, sy, qx, qy);
    __syncthreads();
    if (wv == 0) {
        float fx = 0.f, fy = 0.f, gx = 0.f, gy = 0.f;
#pragma unroll
        for (int w = 0; w < 8; ++w) {
            float4 a = red[w][lane];
            fx += a.x; fy += a.y; gx += a.z; gy += a.w;
        }
        float* st = stats + (b & (NREP - 1)) * 256;
        atomicAdd(&st[2 * lane],           fx);
        atomicAdd(&st[2 * lane + 1],       fy);
        atomicAdd(&st[128 + 2 * lane],     gx);
        atomicAdd(&st[128 + 2 * lane + 1], gy);
    }
}

// ---------------------------------------------------------------------------
// K6: out = relu(bn(h1)) @ W2^T + b2  (persistent-B MFMA, W2 split inline,
// grid-strided, prefetch), in-place on d_out. Reduces NREP replicas first.
// ---------------------------------------------------------------------------
__launch_bounds__(256)
__global__ void gemm2_mfma(float* __restrict__ h1out,
                           const float* __restrict__ W2,
                           const float* __restrict__ b2, const float* __restrict__ stats,
                           const float* __restrict__ gamma, const float* __restrict__ beta) {
    __shared__ unsigned short sH[TM][136];
    __shared__ unsigned short sL[TM][136];
    __shared__ float sScale[128];
    __shared__ float sShift[128];
    const int tid = threadIdx.x;
    const int wv  = tid >> 6;
    const int ln  = tid & 63;
    const int lc  = ln & 15;
    const int qd  = ln >> 4;
    const int sr  = tid >> 5;      // staging row base (0..7)
    const int sc4 = tid & 31;      // staging float4 chunk

    if (tid < 128) {
        float s = 0.f, q = 0.f;
#pragma unroll
        for (int r = 0; r < NREP; ++r) {
            s += stats[r * 256 + tid];
            q += stats[r * 256 + 128 + tid];
        }
        float mean = s * (1.0f / N_NODES);
        float var  = fmaxf(q * (1.0f / N_NODES) - mean * mean, 0.0f);
        float sc   = gamma[tid] * rsqrtf(var + BN_EPS);
        sScale[tid] = sc;
        sShift[tid] = beta[tid] - mean * sc;
    }

    short8 Bh[4][2], Bl[4][2];
#pragma unroll
    for (int kk = 0; kk < 4; ++kk)
#pragma unroll
        for (int tl = 0; tl < 2; ++tl) {
            int woff = (wv * 32 + tl * 16 + lc) * D + kk * 32 + qd * 8;
            split8(W2 + woff, &Bh[kk][tl], &Bl[kk][tl]);
        }
    float bb[2];
    bb[0] = b2[wv * 32 + lc];
    bb[1] = b2[wv * 32 + 16 + lc];

    __syncthreads();   // sScale/sShift ready

    float4 pf[8];
    int tile = blockIdx.x;
#pragma unroll
    for (int i = 0; i < 8; ++i) {
        int gr = tile * TM + sr + i * 8;
        pf[i] = make_float4(0.f, 0.f, 0.f, 0.f);
        if (gr < N_NODES)
            pf[i] = *(const float4*)(h1out + (long long)gr * D + sc4 * 4);
    }

    while (tile < NT) {
        float4 scv = *(const float4*)&sScale[sc4 * 4];
        float4 shv = *(const float4*)&sShift[sc4 * 4];
#pragma unroll
        for (int i = 0; i < 8; ++i) {
            int gr = tile * TM + sr + i * 8;
            float4 v = pf[i];
            if (gr < N_NODES) {
                v.x = fmaxf(0.f, fmaf(v.x, scv.x, shv.x));
                v.y = fmaxf(0.f, fmaf(v.y, scv.y, shv.y));
                v.z = fmaxf(0.f, fmaf(v.z, scv.z, shv.z));
                v.w = fmaxf(0.f, fmaf(v.w, scv.w, shv.w));
            } else {
                v = make_float4(0.f, 0.f, 0.f, 0.f);
            }
            unsigned short h0 = bf_hi(v.x), h1b = bf_hi(v.y), h2 = bf_hi(v.z), h3 = bf_hi(v.w);
            unsigned short l0 = bf_hi(v.x - bf_val(h0)), l1 = bf_hi(v.y - bf_val(h1b));
            unsigned short l2 = bf_hi(v.z - bf_val(h2)), l3 = bf_hi(v.w - bf_val(h3));
            int r = sr + i * 8;
            *(uint2*)&sH[r][sc4 * 4] = make_uint2((unsigned)h0 | ((unsigned)h1b << 16),
                                                  (unsigned)h2 | ((unsigned)h3 << 16));
            *(uint2*)&sL[r][sc4 * 4] = make_uint2((unsigned)l0 | ((unsigned)l1 << 16),
                                                  (unsigned)l2 | ((unsigned)l3 << 16));
        }
        __syncthreads();
        int nxt = tile + GGRID;
        if (nxt < NT) {
#pragma unroll
            for (int i = 0; i < 8; ++i) {
                int gr = nxt * TM + sr + i * 8;
                pf[i] = make_float4(0.f, 0.f, 0.f, 0.f);
                if (gr < N_NODES)
                    pf[i] = *(const float4*)(h1out + (long long)gr * D + sc4 * 4);
            }
        }

        f32x4 acc[4][2];
#pragma unroll
        for (int m = 0; m < 4; ++m)
#pragma unroll
            for (int tl = 0; tl < 2; ++tl) acc[m][tl] = (f32x4){0.f, 0.f, 0.f, 0.f};

#pragma unroll
        for (int kk = 0; kk < 4; ++kk) {
#pragma unroll
            for (int m = 0; m < 4; ++m) {
                short8 ah = *(const short8*)&sH[m * 16 + lc][kk * 32 + qd * 8];
                short8 al = *(const short8*)&sL[m * 16 + lc][kk * 32 + qd * 8];
#pragma unroll
                for (int tl = 0; tl < 2; ++tl) {
                    acc[m][tl] = __builtin_amdgcn_mfma_f32_16x16x32_bf16(ah, Bh[kk][tl], acc[m][tl], 0, 0, 0);
                    acc[m][tl] = __builtin_amdgcn_mfma_f32_16x16x32_bf16(al, Bh[kk][tl], acc[m][tl], 0, 0, 0);
                    acc[m][tl] = __builtin_amdgcn_mfma_f32_16x16x32_bf16(ah, Bl[kk][tl], acc[m][tl], 0, 0, 0);
                }
            }
        }

        const int row0 = tile * TM;
#pragma unroll
        for (int m = 0; m < 4; ++m)
#pragma unroll
            for (int tl = 0; tl < 2; ++tl) {
                int col = wv * 32 + tl * 16 + lc;
#pragma unroll
                for (int r = 0; r < 4; ++r) {
                    int grow = row0 + m * 16 + qd * 4 + r;
                    if (grow < N_NODES)
                        h1out[(long long)grow * D + col] = acc[m][tl][r] + bb[tl];
                }
            }
        __syncthreads();
        tile = nxt;
    }
}

// ---------------------------------------------------------------------------
extern "C" void kernel_launch(void* const* d_in, const int* in_sizes, int n_in,
                              void* d_out, int out_size, void* d_ws, size_t ws_size,
                              hipStream_t stream) {
    const float* x     = (const float*)d_in[0];
    const int*   ei    = (const int*)d_in[1];
    const float* eps_p = (const float*)d_in[2];
    const float* W1    = (const float*)d_in[3];
    const float* b1    = (const float*)d_in[4];
    const float* gamma = (const float*)d_in[5];
    const float* beta  = (const float*)d_in[6];
    const float* W2    = (const float*)d_in[7];
    const float* b2    = (const float*)d_in[8];

    // workspace layout (~40.7 MB)
    __half* yh   = (__half*)d_ws;                             // N*128 halfs: y mirror (25.6MB)
    float*  stats = (float*)(yh + (long long)N_NODES * D);    // NREP*256 floats (32KB)
    int*    gcur  = (int*)(stats + NREP * 256);               // 1024 ints (adjacent: one memset)
    int*    pairs = gcur + 1024;                              // NB*SLOT ints (15.0MB)

    float* out = (float*)d_out;                               // h1 scratch + final out

    // zero stats + gcur (36 KB, graph-capture-safe async memset)
    hipMemsetAsync(stats, 0, (NREP * 256 + 1024) * sizeof(int), stream);

    {   // F1: fused gemm0 (blocks 0..781) + edge partition (blocks 782..1563)
        fused_pg<<<GGRID + 782, 256, 0, stream>>>(x, W1, yh, ei, gcur, pairs);
    }
    {   // K4: fused bucket-build + gather -> h1 (d_out) + BN stats
        bucket_gather<<<NB, 512, 0, stream>>>(yh, pairs, gcur, eps_p, b1, out, stats);
    }
    {   // K6: BN finalize + ReLU + persistent-B MFMA GEMM2, in-place on d_out
        gemm2_mfma<<<GGRID, 256, 0, stream>>>(out, W2, b2, stats, gamma, beta);
    }
}

// Round 14
// 319.609 us; speedup vs baseline: 1.1263x; 1.0138x over previous
//
#include <hip/hip_runtime.h>
#include <hip/hip_fp16.h>

#define N_NODES 100000
#define EDGES   1600000
#define D       128
#define BN_EPS  1e-5f
#define TM      64                        // rows per GEMM tile
#define NT      ((N_NODES + TM - 1) / TM) // 1563 row tiles
#define GGRID   782                       // gemm0 logical grid (2 tiles/block)
#define GGRID2  1024                      // gemm2 grid: exactly 4 blocks/CU
#define NB      782                       // 128-node buckets
#define SLOT    4800                      // per-bucket slot: mean 4092 + 11 sigma
#define L1E     8                         // ei entries per thread (emits 2 pairs each)
#define L1TILE  (256 * L1E)               // 2048 ei entries per tile -> 782 tiles
#define NREP    32                        // BN-stat replicas

typedef __attribute__((ext_vector_type(8))) short short8;
typedef __attribute__((ext_vector_type(4))) float f32x4;

__device__ __forceinline__ unsigned short bf_hi(float f) {
    unsigned u = __float_as_uint(f);
    unsigned t = u + 0x7FFF + ((u >> 16) & 1);
    return (unsigned short)(t >> 16);
}
__device__ __forceinline__ float bf_val(unsigned short h) {
    return __uint_as_float(((unsigned)h) << 16);
}
// split 8 contiguous fp32 into bf16 hi/lo fragments (for inline W staging)
__device__ __forceinline__ void split8(const float* __restrict__ p, short8* hi, short8* lo) {
    short8 h, l;
#pragma unroll
    for (int i = 0; i < 8; ++i) {
        float f = p[i];
        unsigned short hh = bf_hi(f);
        ((unsigned short*)&h)[i] = (short)hh;
        ((unsigned short*)&l)[i] = (short)bf_hi(f - bf_val(hh));
    }
    *hi = h; *lo = l;
}

// ---------------------------------------------------------------------------
// F1: heterogeneous fused kernel, ROLE-INTERLEAVED for co-residency:
//   even blocks (bid>>1 in [0,782)) : gemm0  y = x @ W1^T -> fp16 mirror
//   odd  blocks (bid>>1 in [0,782)) : edge partition into 128-node buckets
// Interleave keeps ~half of each CU's slots on short-lived partition blocks
// (which drain continuously) instead of serializing them behind persistent
// gemm blocks. pairs entry: (local_dst<<17) | src
// ---------------------------------------------------------------------------
__launch_bounds__(256)
__global__ void fused_pg(const float* __restrict__ x,
                         const float* __restrict__ W1,
                         __half* __restrict__ yh,
                         const int* __restrict__ ei, int* __restrict__ gcur,
                         int* __restrict__ pairs) {
    __shared__ unsigned short sH[TM][136];
    __shared__ unsigned short sL[TM][136];
    const int tid = threadIdx.x;
    const int role = blockIdx.x & 1;
    const int rid  = blockIdx.x >> 1;    // 0..781 within role

    if (role) {
        // ---------------- partition path ----------------
        int* cnt   = (int*)&sH[0][0];        // 782 ints
        int* cbase = cnt + NB;               // 782 ints  (6.3 KB total, aliased)
        for (int i = tid; i < NB; i += 256) cnt[i] = 0;
        __syncthreads();

        int bbA[L1E], rrA[L1E], pkA[L1E];
        int bbB[L1E], rrB[L1E], pkB[L1E];
        const int t0 = rid * L1TILE + tid;
#pragma unroll
        for (int j = 0; j < L1E; ++j) {
            int t = t0 + j * 256;
            bbA[j] = -1;
            bbB[j] = -1;
            if (t < EDGES) {
                int s = ei[t];
                int d = ei[EDGES + t];
                bbA[j] = d >> 7;                     // aggr[d] += y[s]
                pkA[j] = ((d & 127) << 17) | s;
                rrA[j] = atomicAdd(&cnt[bbA[j]], 1);
                bbB[j] = s >> 7;                     // aggr[s] += y[d]
                pkB[j] = ((s & 127) << 17) | d;
                rrB[j] = atomicAdd(&cnt[bbB[j]], 1);
            }
        }
        __syncthreads();
        for (int i = tid; i < NB; i += 256) {
            int c = cnt[i];
            cbase[i] = c ? (i * SLOT + atomicAdd(&gcur[i], c)) : 0;
        }
        __syncthreads();
#pragma unroll
        for (int j = 0; j < L1E; ++j) {
            if (bbA[j] >= 0) {
                pairs[cbase[bbA[j]] + rrA[j]] = pkA[j];
                pairs[cbase[bbB[j]] + rrB[j]] = pkB[j];
            }
        }
        return;
    }

    // ---------------- gemm0 path ----------------
    const int wv  = tid >> 6;
    const int ln  = tid & 63;
    const int lc  = ln & 15;
    const int qd  = ln >> 4;
    const int sr  = tid >> 5;      // staging row base (0..7)
    const int sc4 = tid & 31;      // staging float4 chunk

    short8 Bh[4][2], Bl[4][2];
#pragma unroll
    for (int kk = 0; kk < 4; ++kk)
#pragma unroll
        for (int tl = 0; tl < 2; ++tl) {
            int woff = (wv * 32 + tl * 16 + lc) * D + kk * 32 + qd * 8;
            split8(W1 + woff, &Bh[kk][tl], &Bl[kk][tl]);
        }

    float4 pf[8];
    int tile = rid;
#pragma unroll
    for (int i = 0; i < 8; ++i) {
        int gr = tile * TM + sr + i * 8;
        pf[i] = make_float4(0.f, 0.f, 0.f, 0.f);
        if (gr < N_NODES)
            pf[i] = *(const float4*)(x + (long long)gr * D + sc4 * 4);
    }

    while (tile < NT) {
#pragma unroll
        for (int i = 0; i < 8; ++i) {
            float4 v = pf[i];
            unsigned short h0 = bf_hi(v.x), h1b = bf_hi(v.y), h2 = bf_hi(v.z), h3 = bf_hi(v.w);
            unsigned short l0 = bf_hi(v.x - bf_val(h0)), l1 = bf_hi(v.y - bf_val(h1b));
            unsigned short l2 = bf_hi(v.z - bf_val(h2)), l3 = bf_hi(v.w - bf_val(h3));
            int r = sr + i * 8;
            *(uint2*)&sH[r][sc4 * 4] = make_uint2((unsigned)h0 | ((unsigned)h1b << 16),
                                                  (unsigned)h2 | ((unsigned)h3 << 16));
            *(uint2*)&sL[r][sc4 * 4] = make_uint2((unsigned)l0 | ((unsigned)l1 << 16),
                                                  (unsigned)l2 | ((unsigned)l3 << 16));
        }
        __syncthreads();
        int nxt = tile + GGRID;
        if (nxt < NT) {
#pragma unroll
            for (int i = 0; i < 8; ++i) {
                int gr = nxt * TM + sr + i * 8;
                pf[i] = make_float4(0.f, 0.f, 0.f, 0.f);
                if (gr < N_NODES)
                    pf[i] = *(const float4*)(x + (long long)gr * D + sc4 * 4);
            }
        }

        f32x4 acc[4][2];
#pragma unroll
        for (int m = 0; m < 4; ++m)
#pragma unroll
            for (int tl = 0; tl < 2; ++tl) acc[m][tl] = (f32x4){0.f, 0.f, 0.f, 0.f};

#pragma unroll
        for (int kk = 0; kk < 4; ++kk) {
#pragma unroll
            for (int m = 0; m < 4; ++m) {
                short8 ah = *(const short8*)&sH[m * 16 + lc][kk * 32 + qd * 8];
                short8 al = *(const short8*)&sL[m * 16 + lc][kk * 32 + qd * 8];
#pragma unroll
                for (int tl = 0; tl < 2; ++tl) {
                    acc[m][tl] = __builtin_amdgcn_mfma_f32_16x16x32_bf16(ah, Bh[kk][tl], acc[m][tl], 0, 0, 0);
                    acc[m][tl] = __builtin_amdgcn_mfma_f32_16x16x32_bf16(al, Bh[kk][tl], acc[m][tl], 0, 0, 0);
                    acc[m][tl] = __builtin_amdgcn_mfma_f32_16x16x32_bf16(ah, Bl[kk][tl], acc[m][tl], 0, 0, 0);
                }
            }
        }

        const int row0 = tile * TM;
#pragma unroll
        for (int m = 0; m < 4; ++m)
#pragma unroll
            for (int tl = 0; tl < 2; ++tl) {
                int col = wv * 32 + tl * 16 + lc;
#pragma unroll
                for (int r = 0; r < 4; ++r) {
                    int grow = row0 + m * 16 + qd * 4 + r;
                    if (grow < N_NODES)
                        yh[(long long)grow * D + col] = __float2half(acc[m][tl][r]);
                }
            }
        __syncthreads();
        tile = nxt;
    }
}

// ---------------------------------------------------------------------------
// K4: fused bucket-build + gather. One block per 128-node bucket (512 thr,
// 8 waves). Prologue: read pairs slot into registers (static idx), degree
// count + scan + place sorted adj in LDS. Gather phase: 16 nodes/wave,
// 8-deep pipeline, adj from LDS. BN stats -> NREP replicas.
// ---------------------------------------------------------------------------
__launch_bounds__(512)
__global__ void bucket_gather(const __half* __restrict__ yh,
                              const int* __restrict__ pairs, const int* __restrict__ gcur,
                              const float* __restrict__ eps_p, const float* __restrict__ b1,
                              float* __restrict__ h1, float* __restrict__ stats) {
    __shared__ int sA[SLOT];        // 19.2 KB: sorted adjacency (src ids)
    __shared__ int lc[128];
    __shared__ int cur[128];
    __shared__ int nofs[129];
    __shared__ float4 red[8][64];   // 8 KB
    const int b    = blockIdx.x;
    const int tid  = threadIdx.x;
    const int base = b * SLOT;
    const int m    = min(gcur[b], SLOT);

    // prologue: slot -> registers (statically indexed), count, scan, place
    int my[10];
#pragma unroll
    for (int k = 0; k < 10; ++k) {
        int i = tid + k * 512;
        my[k] = (i < m) ? pairs[base + i] : -1;
    }
    if (tid < 128) lc[tid] = 0;
    __syncthreads();
#pragma unroll
    for (int k = 0; k < 10; ++k)
        if (my[k] >= 0) atomicAdd(&lc[my[k] >> 17], 1);
    __syncthreads();
    int v = (tid < 128) ? lc[tid] : 0;
    for (int d = 1; d < 128; d <<= 1) {
        int u = (tid >= d && tid < 128) ? lc[tid - d] : 0;
        __syncthreads();
        if (tid < 128) lc[tid] += u;
        __syncthreads();
    }
    if (tid < 128) {
        int e0 = lc[tid] - v;          // exclusive scan, 0-based in bucket
        cur[tid]  = e0;
        nofs[tid] = e0;
        if (tid == 127) nofs[128] = lc[127];
    }
    __syncthreads();
#pragma unroll
    for (int k = 0; k < 10; ++k)
        if (my[k] >= 0) {
            int r = atomicAdd(&cur[my[k] >> 17], 1);
            sA[r] = my[k] & 0x1FFFF;
        }
    __syncthreads();

    // gather phase
    const int wv   = tid >> 6;      // 0..7
    const int lane = tid & 63;
    const __half2* xp = (const __half2*)yh;
    const float sc = 2.0f + eps_p[0];
    const float2 b1c = ((const float2*)b1)[lane];
    float sx = 0.f, sy = 0.f, qx = 0.f, qy = 0.f;

    for (int ln = wv * 16; ln < wv * 16 + 16; ++ln) {
        int node = (b << 7) + ln;
        if (node >= N_NODES) break;
        int nb = nofs[ln];
        int ne = nofs[ln + 1];
        float ax = 0.f, ay = 0.f;
        int i = nb;
        for (; i + 8 <= ne; i += 8) {
            int n0 = sA[i],     n1 = sA[i + 1], n2 = sA[i + 2], n3 = sA[i + 3];
            int n4 = sA[i + 4], n5 = sA[i + 5], n6 = sA[i + 6], n7 = sA[i + 7];
            __half2 v0 = xp[(unsigned)n0 * 64u + lane];
            __half2 v1 = xp[(unsigned)n1 * 64u + lane];
            __half2 v2 = xp[(unsigned)n2 * 64u + lane];
            __half2 v3 = xp[(unsigned)n3 * 64u + lane];
            __half2 v4 = xp[(unsigned)n4 * 64u + lane];
            __half2 v5 = xp[(unsigned)n5 * 64u + lane];
            __half2 v6 = xp[(unsigned)n6 * 64u + lane];
            __half2 v7 = xp[(unsigned)n7 * 64u + lane];
            float2 f0 = __half22float2(v0);
            float2 f1 = __half22float2(v1);
            float2 f2 = __half22float2(v2);
            float2 f3 = __half22float2(v3);
            float2 f4 = __half22float2(v4);
            float2 f5 = __half22float2(v5);
            float2 f6 = __half22float2(v6);
            float2 f7 = __half22float2(v7);
            ax += ((f0.x + f1.x) + (f2.x + f3.x)) + ((f4.x + f5.x) + (f6.x + f7.x));
            ay += ((f0.y + f1.y) + (f2.y + f3.y)) + ((f4.y + f5.y) + (f6.y + f7.y));
        }
        for (; i + 4 <= ne; i += 4) {
            int n0 = sA[i], n1 = sA[i + 1], n2 = sA[i + 2], n3 = sA[i + 3];
            __half2 v0 = xp[(unsigned)n0 * 64u + lane];
            __half2 v1 = xp[(unsigned)n1 * 64u + lane];
            __half2 v2 = xp[(unsigned)n2 * 64u + lane];
            __half2 v3 = xp[(unsigned)n3 * 64u + lane];
            float2 f0 = __half22float2(v0);
            float2 f1 = __half22float2(v1);
            float2 f2 = __half22float2(v2);
            float2 f3 = __half22float2(v3);
            ax += (f0.x + f1.x) + (f2.x + f3.x);
            ay += (f0.y + f1.y) + (f2.y + f3.y);
        }
        for (; i < ne; ++i) {
            __half2 vv = xp[(unsigned)sA[i] * 64u + lane];
            float2 f = __half22float2(vv);
            ax += f.x;
            ay += f.y;
        }
        float2 ys = __half22float2(xp[(unsigned)node * 64u + lane]);
        float ox = fmaf(sc, ys.x, ax) + b1c.x;
        float oy = fmaf(sc, ys.y, ay) + b1c.y;
        ((float2*)h1)[(long long)node * 64 + lane] = make_float2(ox, oy);
        sx += ox; sy += oy;
        qx += ox * ox; qy += oy * oy;
    }

    red[wv][lane] = make_float4(sx, sy, qx, qy);
    __syncthreads();
    if (wv == 0) {
        float fx = 0.f, fy = 0.f, gx = 0.f, gy = 0.f;
#pragma unroll
        for (int w = 0; w < 8; ++w) {
            float4 a = red[w][lane];
            fx += a.x; fy += a.y; gx += a.z; gy += a.w;
        }
        float* st = stats + (b & (NREP - 1)) * 256;
        atomicAdd(&st[2 * lane],           fx);
        atomicAdd(&st[2 * lane + 1],       fy);
        atomicAdd(&st[128 + 2 * lane],     gx);
        atomicAdd(&st[128 + 2 * lane + 1], gy);
    }
}

// ---------------------------------------------------------------------------
// K6: out = relu(bn(h1)) @ W2^T + b2  (persistent-B MFMA, W2 split inline,
// grid-strided over 1024 blocks = 4/CU), in-place on d_out.
// ---------------------------------------------------------------------------
__launch_bounds__(256)
__global__ void gemm2_mfma(float* __restrict__ h1out,
                           const float* __restrict__ W2,
                           const float* __restrict__ b2, const float* __restrict__ stats,
                           const float* __restrict__ gamma, const float* __restrict__ beta) {
    __shared__ unsigned short sH[TM][136];
    __shared__ unsigned short sL[TM][136];
    __shared__ float sScale[128];
    __shared__ float sShift[128];
    const int tid = threadIdx.x;
    const int wv  = tid >> 6;
    const int ln  = tid & 63;
    const int lc  = ln & 15;
    const int qd  = ln >> 4;
    const int sr  = tid >> 5;      // staging row base (0..7)
    const int sc4 = tid & 31;      // staging float4 chunk

    if (tid < 128) {
        float s = 0.f, q = 0.f;
#pragma unroll
        for (int r = 0; r < NREP; ++r) {
            s += stats[r * 256 + tid];
            q += stats[r * 256 + 128 + tid];
        }
        float mean = s * (1.0f / N_NODES);
        float var  = fmaxf(q * (1.0f / N_NODES) - mean * mean, 0.0f);
        float sc   = gamma[tid] * rsqrtf(var + BN_EPS);
        sScale[tid] = sc;
        sShift[tid] = beta[tid] - mean * sc;
    }

    short8 Bh[4][2], Bl[4][2];
#pragma unroll
    for (int kk = 0; kk < 4; ++kk)
#pragma unroll
        for (int tl = 0; tl < 2; ++tl) {
            int woff = (wv * 32 + tl * 16 + lc) * D + kk * 32 + qd * 8;
            split8(W2 + woff, &Bh[kk][tl], &Bl[kk][tl]);
        }
    float bb[2];
    bb[0] = b2[wv * 32 + lc];
    bb[1] = b2[wv * 32 + 16 + lc];

    __syncthreads();   // sScale/sShift ready

    float4 pf[8];
    int tile = blockIdx.x;
#pragma unroll
    for (int i = 0; i < 8; ++i) {
        int gr = tile * TM + sr + i * 8;
        pf[i] = make_float4(0.f, 0.f, 0.f, 0.f);
        if (gr < N_NODES && tile < NT)
            pf[i] = *(const float4*)(h1out + (long long)gr * D + sc4 * 4);
    }

    while (tile < NT) {
        float4 scv = *(const float4*)&sScale[sc4 * 4];
        float4 shv = *(const float4*)&sShift[sc4 * 4];
#pragma unroll
        for (int i = 0; i < 8; ++i) {
            int gr = tile * TM + sr + i * 8;
            float4 v = pf[i];
            if (gr < N_NODES) {
                v.x = fmaxf(0.f, fmaf(v.x, scv.x, shv.x));
                v.y = fmaxf(0.f, fmaf(v.y, scv.y, shv.y));
                v.z = fmaxf(0.f, fmaf(v.z, scv.z, shv.z));
                v.w = fmaxf(0.f, fmaf(v.w, scv.w, shv.w));
            } else {
                v = make_float4(0.f, 0.f, 0.f, 0.f);
            }
            unsigned short h0 = bf_hi(v.x), h1b = bf_hi(v.y), h2 = bf_hi(v.z), h3 = bf_hi(v.w);
            unsigned short l0 = bf_hi(v.x - bf_val(h0)), l1 = bf_hi(v.y - bf_val(h1b));
            unsigned short l2 = bf_hi(v.z - bf_val(h2)), l3 = bf_hi(v.w - bf_val(h3));
            int r = sr + i * 8;
            *(uint2*)&sH[r][sc4 * 4] = make_uint2((unsigned)h0 | ((unsigned)h1b << 16),
                                                  (unsigned)h2 | ((unsigned)h3 << 16));
            *(uint2*)&sL[r][sc4 * 4] = make_uint2((unsigned)l0 | ((unsigned)l1 << 16),
                                                  (unsigned)l2 | ((unsigned)l3 << 16));
        }
        __syncthreads();
        int nxt = tile + GGRID2;
        if (nxt < NT) {
#pragma unroll
            for (int i = 0; i < 8; ++i) {
                int gr = nxt * TM + sr + i * 8;
                pf[i] = make_float4(0.f, 0.f, 0.f, 0.f);
                if (gr < N_NODES)
                    pf[i] = *(const float4*)(h1out + (long long)gr * D + sc4 * 4);
            }
        }

        f32x4 acc[4][2];
#pragma unroll
        for (int m = 0; m < 4; ++m)
#pragma unroll
            for (int tl = 0; tl < 2; ++tl) acc[m][tl] = (f32x4){0.f, 0.f, 0.f, 0.f};

#pragma unroll
        for (int kk = 0; kk < 4; ++kk) {
#pragma unroll
            for (int m = 0; m < 4; ++m) {
                short8 ah = *(const short8*)&sH[m * 16 + lc][kk * 32 + qd * 8];
                short8 al = *(const short8*)&sL[m * 16 + lc][kk * 32 + qd * 8];
#pragma unroll
                for (int tl = 0; tl < 2; ++tl) {
                    acc[m][tl] = __builtin_amdgcn_mfma_f32_16x16x32_bf16(ah, Bh[kk][tl], acc[m][tl], 0, 0, 0);
                    acc[m][tl] = __builtin_amdgcn_mfma_f32_16x16x32_bf16(al, Bh[kk][tl], acc[m][tl], 0, 0, 0);
                    acc[m][tl] = __builtin_amdgcn_mfma_f32_16x16x32_bf16(ah, Bl[kk][tl], acc[m][tl], 0, 0, 0);
                }
            }
        }

        const int row0 = tile * TM;
#pragma unroll
        for (int m = 0; m < 4; ++m)
#pragma unroll
            for (int tl = 0; tl < 2; ++tl) {
                int col = wv * 32 + tl * 16 + lc;
#pragma unroll
                for (int r = 0; r < 4; ++r) {
                    int grow = row0 + m * 16 + qd * 4 + r;
                    if (grow < N_NODES)
                        h1out[(long long)grow * D + col] = acc[m][tl][r] + bb[tl];
                }
            }
        __syncthreads();
        tile = nxt;
    }
}

// ---------------------------------------------------------------------------
extern "C" void kernel_launch(void* const* d_in, const int* in_sizes, int n_in,
                              void* d_out, int out_size, void* d_ws, size_t ws_size,
                              hipStream_t stream) {
    const float* x     = (const float*)d_in[0];
    const int*   ei    = (const int*)d_in[1];
    const float* eps_p = (const float*)d_in[2];
    const float* W1    = (const float*)d_in[3];
    const float* b1    = (const float*)d_in[4];
    const float* gamma = (const float*)d_in[5];
    const float* beta  = (const float*)d_in[6];
    const float* W2    = (const float*)d_in[7];
    const float* b2    = (const float*)d_in[8];

    // workspace layout (~40.7 MB)
    __half* yh   = (__half*)d_ws;                             // N*128 halfs: y mirror (25.6MB)
    float*  stats = (float*)(yh + (long long)N_NODES * D);    // NREP*256 floats (32KB)
    int*    gcur  = (int*)(stats + NREP * 256);               // 1024 ints (adjacent: one memset)
    int*    pairs = gcur + 1024;                              // NB*SLOT ints (15.0MB)

    float* out = (float*)d_out;                               // h1 scratch + final out

    // zero stats + gcur (36 KB, graph-capture-safe async memset)
    hipMemsetAsync(stats, 0, (NREP * 256 + 1024) * sizeof(int), stream);

    {   // F1: role-interleaved fused gemm0 + edge partition
        fused_pg<<<2 * GGRID, 256, 0, stream>>>(x, W1, yh, ei, gcur, pairs);
    }
    {   // K4: fused bucket-build + gather -> h1 (d_out) + BN stats
        bucket_gather<<<NB, 512, 0, stream>>>(yh, pairs, gcur, eps_p, b1, out, stats);
    }
    {   // K6: BN finalize + ReLU + persistent-B MFMA GEMM2, in-place on d_out
        gemm2_mfma<<<GGRID2, 256, 0, stream>>>(out, W2, b2, stats, gamma, beta);
    }
}